// Round 13
// baseline (607.043 us; speedup 1.0000x reference)
//
#include <hip/hip_runtime.h>
#include <hip/hip_fp16.h>

#define T_DIM 2048
#define B_DIM 64
#define I_DIM 128
#define H_DIM 256
#define L_DIM 6
#define C_DIM 100
#define M_DIM (T_DIM * B_DIM)   // 131072 rows
#define S_DIM (B_DIM * H_DIM)   // 16384 chains
#define CB 16                   // chains per scan block
#define YSTR2 1089              // u32 stride per chain in LDS (64*17+1; ==1 mod 32)

typedef unsigned short u16;
typedef unsigned int   u32;
typedef _Float16 f16;
typedef f16   f16x8 __attribute__((ext_vector_type(8)));
typedef float f32x4 __attribute__((ext_vector_type(4)));

__device__ __forceinline__ float h2f(u16 u) { return __half2float(__ushort_as_half(u)); }
__device__ __forceinline__ u16   f2h(float f) { return __half_as_ushort(__float2half(f)); }
__device__ __forceinline__ u32   packh(float a, float b) {
    return (u32)f2h(a) | ((u32)f2h(b) << 16);
}

// ---------------- weight repack (all layers, one dispatch) + zero the bn counter
__global__ __launch_bounds__(256)
void wt_convert_all(const float* __restrict__ W0, const float* __restrict__ Wl,
                    u16* __restrict__ Wt0, u16* __restrict__ Wtl, u32* __restrict__ cnt) {
    if (blockIdx.x == 0 && threadIdx.x == 0) *cnt = 0;
    int id = blockIdx.x * 256 + threadIdx.x;
    const float* W; u16* outp; int NK, lg, chunk;
    if (id < 4096) { W = W0; outp = Wt0; NK = 4; lg = 2; chunk = id; }
    else {
        int r = id - 4096;
        int l = r >> 13;
        if (l >= 5) return;
        chunk = r & 8191;
        W = Wl + (size_t)l * H_DIM * H_DIM;
        outp = Wtl + (size_t)l * 65536;
        NK = 8; lg = 3;
    }
    int lane = chunk & 63;
    int rest = chunk >> 6;
    int n  = rest & 3; rest >>= 2;
    int kc = rest & (NK - 1);
    int w  = rest >> lg;
    int col = w * 64 + n + 4 * (lane & 15);
    int kb  = kc * 32 + (lane >> 4) * 8;
    u32 o[4];
    #pragma unroll
    for (int j = 0; j < 4; ++j)
        o[j] = packh(W[(size_t)(kb + 2 * j) * H_DIM + col],
                     W[(size_t)(kb + 2 * j + 1) * H_DIM + col]);
    *(uint4*)(outp + (size_t)chunk * 8) = uint4{o[0], o[1], o[2], o[3]};
}

// ---------------- MFMA GEMM, W-in-registers, fused bias + BN partial stats (f32).
template<int K, bool AF32>
__global__ __launch_bounds__(256, 2)
void gemm_mfma(const void* Asrc, const u16* __restrict__ Wtc,
               const float* __restrict__ bias, u16* Yout, float2* __restrict__ psum) {
    constexpr int NK = K / 32;
    constexpr int AROWB = AF32 ? 272 : 528;
    __shared__ char Alds[64 * AROWB];
    const int tid  = threadIdx.x;
    const int lane = tid & 63;
    const int wave = tid >> 6;
    const int c    = lane & 15;
    const int g    = lane >> 4;
    const size_t brow = (size_t)blockIdx.x * 64;

    f16x8 wreg[NK][4];
    {
        const u16* base = Wtc + ((size_t)wave * NK * 4 * 64 + lane) * 8;
        #pragma unroll
        for (int kc = 0; kc < NK; ++kc)
            #pragma unroll
            for (int n = 0; n < 4; ++n)
                wreg[kc][n] = *(const f16x8*)(base + (size_t)(kc * 4 + n) * 64 * 8);
    }
    {
        const char* A = (const char*)Asrc + brow * 512;
        #pragma unroll
        for (int i = 0; i < 8; ++i) {
            int off = i * 4096 + tid * 16;
            int row = off >> 9, inb = off & 511;
            if (AF32) {
                float4 v = *(const float4*)(A + off);
                uint2 o = { packh(v.x, v.y), packh(v.z, v.w) };
                *(uint2*)(Alds + row * AROWB + (inb >> 1)) = o;
            } else {
                *(uint4*)(Alds + row * AROWB + inb) = *(const uint4*)(A + off);
            }
        }
    }
    __syncthreads();

    f32x4 acc[4][4];
    #pragma unroll
    for (int m = 0; m < 4; ++m)
        #pragma unroll
        for (int n = 0; n < 4; ++n)
            acc[m][n] = f32x4{0.f, 0.f, 0.f, 0.f};

    #pragma unroll
    for (int kc = 0; kc < NK; ++kc) {
        f16x8 afr[4];
        #pragma unroll
        for (int m = 0; m < 4; ++m) {
            int row = m * 16 + c;
            afr[m] = *(const f16x8*)(Alds + row * AROWB + kc * 64 + (g << 4));
        }
        #pragma unroll
        for (int m = 0; m < 4; ++m)
            #pragma unroll
            for (int n = 0; n < 4; ++n)
                acc[m][n] = __builtin_amdgcn_mfma_f32_16x16x32_f16(afr[m], wreg[kc][n], acc[m][n], 0, 0, 0);
    }

    float4 bv = *(const float4*)(bias + wave * 64 + 4 * c);
    float bb[4] = {bv.x, bv.y, bv.z, bv.w};
    float s[4] = {}, q[4] = {};
    #pragma unroll
    for (int m = 0; m < 4; ++m) {
        #pragma unroll
        for (int r = 0; r < 4; ++r) {
            float y0 = acc[m][0][r] + bb[0];
            float y1 = acc[m][1][r] + bb[1];
            float y2 = acc[m][2][r] + bb[2];
            float y3 = acc[m][3][r] + bb[3];
            s[0] += y0; q[0] = fmaf(y0, y0, q[0]);
            s[1] += y1; q[1] = fmaf(y1, y1, q[1]);
            s[2] += y2; q[2] = fmaf(y2, y2, q[2]);
            s[3] += y3; q[3] = fmaf(y3, y3, q[3]);
            size_t grow = brow + m * 16 + g * 4 + r;
            ushort4 o = { f2h(y0), f2h(y1), f2h(y2), f2h(y3) };
            *(ushort4*)(Yout + grow * H_DIM + wave * 64 + 4 * c) = o;
        }
    }
    #pragma unroll
    for (int n = 0; n < 4; ++n) {
        s[n] += __shfl_xor(s[n], 16, 64); s[n] += __shfl_xor(s[n], 32, 64);
        q[n] += __shfl_xor(q[n], 16, 64); q[n] += __shfl_xor(q[n], 32, 64);
    }
    if (g == 0) {
        float2* dst = psum + (size_t)blockIdx.x * 256 + wave * 64 + 4 * c;
        #pragma unroll
        for (int n = 0; n < 4; ++n) dst[n] = float2{s[n], q[n]};
    }
}

// ---------------- BN reduce + finalize (last-block pattern, deterministic)
__global__ __launch_bounds__(256)
void bn_reduce_fin(const float2* __restrict__ psum, float2* __restrict__ p2,
                   const float* __restrict__ gamma, const float* __restrict__ beta,
                   float* __restrict__ af, float* __restrict__ shf, u32* cnt) {
    const int cch = threadIdx.x, blk = blockIdx.x;
    float s = 0.f, q = 0.f;
    for (int i = 0; i < 32; ++i) {
        float2 p = psum[(size_t)(blk * 32 + i) * 256 + cch];
        s += p.x; q += p.y;
    }
    p2[blk * 256 + cch] = float2{s, q};
    __threadfence();
    __shared__ u32 lastFlag;
    if (threadIdx.x == 0) lastFlag = (atomicAdd(cnt, 1) == 63) ? 1u : 0u;
    __syncthreads();
    if (lastFlag) {
        __threadfence();
        float ss = 0.f, qq = 0.f;
        for (int i = 0; i < 64; ++i) {
            float2 v = p2[i * 256 + cch];
            ss += v.x; qq += v.y;
        }
        const float inv = 1.0f / (float)M_DIM;
        float m = ss * inv;
        float v = qq * inv - m * m;
        float a = gamma[cch] * rsqrtf(v + 1e-5f);
        af[cch] = a;
        shf[cch] = fmaf(-m, a, beta[cch]);
        if (threadIdx.x == 0) atomicExch(cnt, 0);
    }
}

// ---- scan compute: one WAVE per chain; lane = chunk of 32 timesteps.
// compose -> KS scan (width 64) over affine-max composites -> apply.
__device__ __forceinline__ void scan_compute_half(
    u32* Y32, int hx, int wave, int lane, int cb,
    const float* __restrict__ af, const float* __restrict__ shf,
    const float* __restrict__ uw) {
    const int ch  = hx * 8 + wave;
    const int cch = (cb * CB + ch) & (H_DIM - 1);
    const float A = af[cch], SH = shf[cch], U = uw[cch];
    u32* base = Y32 + ch * YSTR2 + lane * 17;
    u32 yw[16];
    #pragma unroll
    for (int k = 0; k < 16; ++k) yw[k] = base[k];
    float a = 1.f, b = 0.f, cm = -1e30f;          // identity; -1e30 avoids 0*inf
    #pragma unroll
    for (int k = 0; k < 16; ++k) {
        u32 w = yw[k];
        float yn0 = fmaf(A, h2f((u16)(w & 0xFFFF)), SH);
        a *= U; b = fmaf(U, b, yn0); cm = fmaxf(fmaf(U, cm, yn0), 0.f);
        float yn1 = fmaf(A, h2f((u16)(w >> 16)), SH);
        a *= U; b = fmaf(U, b, yn1); cm = fmaxf(fmaf(U, cm, yn1), 0.f);
    }
    #pragma unroll
    for (int d = 1; d < 64; d <<= 1) {            // Kogge-Stone over 64 chunks
        float ai = __shfl_up(a, d, 64);
        float bi = __shfl_up(b, d, 64);
        float ci = __shfl_up(cm, d, 64);
        if (lane >= d) {                          // outer=(a,b,cm) ∘ inner
            float nb = fmaf(a, bi, b);
            float nc = fmaxf(fmaf(a, ci, b), cm);
            a *= ai; b = nb; cm = nc;
        }
    }
    float bp = __shfl_up(b, 1, 64);
    float cp = __shfl_up(cm, 1, 64);
    float h = (lane == 0) ? 0.f : fmaxf(bp, cp);  // h_in = G_{lane-1}(0)
    #pragma unroll
    for (int k = 0; k < 16; ++k) {
        u32 w = yw[k];
        h = fmaxf(fmaf(U, h, fmaf(A, h2f((u16)(w & 0xFFFF)), SH)), 0.f);
        float hl = h;
        h = fmaxf(fmaf(U, h, fmaf(A, h2f((u16)(w >> 16)), SH)), 0.f);
        base[k] = packh(hl, h);
    }
}

// ---------------- fused scan, software-pipelined halves (T14 async-stage):
// L0 -> w0 -> bar -> {issue L1, comp0} -> bar -> {wb0, w1} -> bar -> comp1
// -> bar -> wb1. H1's HBM latency hides under comp0; wb0 drains under comp1.
__global__ __launch_bounds__(512, 2)
void scan_fused(u16* act, const float* __restrict__ af, const float* __restrict__ shf,
                const float* __restrict__ uw) {
    __shared__ u32 Y32[CB * YSTR2];                           // 69696 B
    const int tid = threadIdx.x;
    const int nwg = gridDim.x;                                // 1024
    const int cb  = (blockIdx.x & 7) * (nwg >> 3) + (blockIdx.x >> 3);  // XCD swizzle
    u32* actG = (u32*)act;
    const int gcb = cb * 8;                                   // 8 u32 cols (16 chains)
    const int wave = tid >> 6, lane = tid & 63;

    // ---- L0: load half 0 (chains 0..7, u32 cols gcb..gcb+3)
    uint4 ve0[2], vo0[2];
    #pragma unroll
    for (int it = 0; it < 2; ++it) {
        int q = tid + it * 512;
        ve0[it] = *(const uint4*)(actG + (size_t)(2 * q)     * 8192 + gcb);
        vo0[it] = *(const uint4*)(actG + (size_t)(2 * q + 1) * 8192 + gcb);
    }
    // ---- w0: transpose-pack into LDS chains 0..7
    #pragma unroll
    for (int it = 0; it < 2; ++it) {
        int q = tid + it * 512;
        int ofs = (q >> 4) * 17 + (q & 15);
        u32 e[4] = {ve0[it].x, ve0[it].y, ve0[it].z, ve0[it].w};
        u32 o[4] = {vo0[it].x, vo0[it].y, vo0[it].z, vo0[it].w};
        #pragma unroll
        for (int m = 0; m < 4; ++m) {
            Y32[(2 * m)     * YSTR2 + ofs] = (e[m] & 0xFFFFu) | (o[m] << 16);
            Y32[(2 * m + 1) * YSTR2 + ofs] = (e[m] >> 16)     | (o[m] & 0xFFFF0000u);
        }
    }
    __syncthreads();

    // ---- L1 issue (latency hides under comp0)
    uint4 ve1[2], vo1[2];
    #pragma unroll
    for (int it = 0; it < 2; ++it) {
        int q = tid + it * 512;
        ve1[it] = *(const uint4*)(actG + (size_t)(2 * q)     * 8192 + gcb + 4);
        vo1[it] = *(const uint4*)(actG + (size_t)(2 * q + 1) * 8192 + gcb + 4);
    }
    // ---- comp0
    scan_compute_half(Y32, 0, wave, lane, cb, af, shf, uw);
    __syncthreads();

    // ---- wb0 (global stores) + w1 (LDS writes for half 1)
    #pragma unroll
    for (int it = 0; it < 2; ++it) {
        int q = tid + it * 512;
        int ofs = (q >> 4) * 17 + (q & 15);
        u32 e[4], o[4];
        #pragma unroll
        for (int m = 0; m < 4; ++m) {
            u32 p0 = Y32[(2 * m)     * YSTR2 + ofs];
            u32 p1 = Y32[(2 * m + 1) * YSTR2 + ofs];
            e[m] = (p0 & 0xFFFFu) | ((p1 & 0xFFFFu) << 16);
            o[m] = (p0 >> 16)     | (p1 & 0xFFFF0000u);
        }
        *(uint4*)(actG + (size_t)(2 * q)     * 8192 + gcb) = uint4{e[0], e[1], e[2], e[3]};
        *(uint4*)(actG + (size_t)(2 * q + 1) * 8192 + gcb) = uint4{o[0], o[1], o[2], o[3]};
    }
    #pragma unroll
    for (int it = 0; it < 2; ++it) {
        int q = tid + it * 512;
        int ofs = (q >> 4) * 17 + (q & 15);
        u32 e[4] = {ve1[it].x, ve1[it].y, ve1[it].z, ve1[it].w};
        u32 o[4] = {vo1[it].x, vo1[it].y, vo1[it].z, vo1[it].w};
        #pragma unroll
        for (int m = 0; m < 4; ++m) {
            Y32[(8 + 2 * m)     * YSTR2 + ofs] = (e[m] & 0xFFFFu) | (o[m] << 16);
            Y32[(8 + 2 * m + 1) * YSTR2 + ofs] = (e[m] >> 16)     | (o[m] & 0xFFFF0000u);
        }
    }
    __syncthreads();

    // ---- comp1
    scan_compute_half(Y32, 1, wave, lane, cb, af, shf, uw);
    __syncthreads();

    // ---- wb1
    #pragma unroll
    for (int it = 0; it < 2; ++it) {
        int q = tid + it * 512;
        int ofs = (q >> 4) * 17 + (q & 15);
        u32 e[4], o[4];
        #pragma unroll
        for (int m = 0; m < 4; ++m) {
            u32 p0 = Y32[(8 + 2 * m)     * YSTR2 + ofs];
            u32 p1 = Y32[(8 + 2 * m + 1) * YSTR2 + ofs];
            e[m] = (p0 & 0xFFFFu) | ((p1 & 0xFFFFu) << 16);
            o[m] = (p0 >> 16)     | (p1 & 0xFFFF0000u);
        }
        *(uint4*)(actG + (size_t)(2 * q)     * 8192 + gcb + 4) = uint4{e[0], e[1], e[2], e[3]};
        *(uint4*)(actG + (size_t)(2 * q + 1) * 8192 + gcb + 4) = uint4{o[0], o[1], o[2], o[3]};
    }
}

// ---------------- classifier: out[B,C] = h_last[B,H] @ Wc[H,C] + bc (f32 out)
__global__ __launch_bounds__(128)
void classifier(const u16* __restrict__ Hlast, const float* __restrict__ Wc,
                const float* __restrict__ bc, float* __restrict__ out) {
    __shared__ float hrow[H_DIM];
    const int b = blockIdx.x, tid = threadIdx.x;
    hrow[tid]       = h2f(Hlast[(size_t)b * H_DIM + tid]);
    hrow[tid + 128] = h2f(Hlast[(size_t)b * H_DIM + tid + 128]);
    __syncthreads();
    if (tid < C_DIM) {
        float s = bc[tid];
        #pragma unroll 8
        for (int hh = 0; hh < H_DIM; ++hh)
            s = fmaf(hrow[hh], Wc[(size_t)hh * C_DIM + tid], s);
        out[(size_t)b * C_DIM + tid] = s;
    }
}

extern "C" void kernel_launch(void* const* d_in, const int* in_sizes, int n_in,
                              void* d_out, int out_size, void* d_ws, size_t ws_size,
                              hipStream_t stream) {
    const float* x     = (const float*)d_in[0];
    const float* W0    = (const float*)d_in[1];
    const float* b0    = (const float*)d_in[2];
    const float* Wl    = (const float*)d_in[3];
    const float* bl    = (const float*)d_in[4];
    const float* u     = (const float*)d_in[5];
    const float* gamma = (const float*)d_in[6];
    const float* beta  = (const float*)d_in[7];
    const float* Wc    = (const float*)d_in[8];
    const float* bc    = (const float*)d_in[9];
    float* out = (float*)d_out;

    // workspace (~72 MB)
    char* ws = (char*)d_ws;
    u16* act = (u16*)ws;                 ws += (size_t)M_DIM * H_DIM * 2;   // 67.1 MB
    u16* Wt0 = (u16*)ws;                 ws += (size_t)32768 * 2;           // 64 KB
    u16* Wtl = (u16*)ws;                 ws += (size_t)5 * 65536 * 2;       // 640 KB
    float2* psum = (float2*)ws;          ws += (size_t)2048 * 256 * 8;      // 4 MB
    float2* p2 = (float2*)ws;            ws += (size_t)64 * 256 * 8;        // 128 KB
    float* af  = (float*)ws;             ws += H_DIM * 4;
    float* shf = (float*)ws;             ws += H_DIM * 4;
    u32* cnt   = (u32*)ws;               ws += 256;

    wt_convert_all<<<176, 256, 0, stream>>>(W0, Wl, Wt0, Wtl, cnt);

    for (int l = 0; l < L_DIM; ++l) {
        if (l == 0) {
            gemm_mfma<I_DIM, true><<<M_DIM / 64, 256, 0, stream>>>(x, Wt0, b0, act, psum);
        } else {
            gemm_mfma<H_DIM, false><<<M_DIM / 64, 256, 0, stream>>>(
                act, Wtl + (size_t)(l - 1) * 65536, bl + (size_t)(l - 1) * H_DIM, act, psum);
        }
        bn_reduce_fin<<<64, 256, 0, stream>>>(psum, p2, gamma + l * H_DIM,
                                              beta + l * H_DIM, af, shf, cnt);
        scan_fused<<<S_DIM / CB, 512, 0, stream>>>(act, af, shf, u + l * H_DIM);
    }
    classifier<<<B_DIM, 128, 0, stream>>>(act + (size_t)(T_DIM - 1) * S_DIM, Wc, bc, out);
}

// Round 14
// 437.557 us; speedup vs baseline: 1.3873x; 1.3873x over previous
//
#include <hip/hip_runtime.h>
#include <hip/hip_fp16.h>

#define T_DIM 2048
#define B_DIM 64
#define I_DIM 128
#define H_DIM 256
#define L_DIM 6
#define C_DIM 100
#define M_DIM (T_DIM * B_DIM)   // 131072 rows
#define S_DIM (B_DIM * H_DIM)   // 16384 chains
#define CB 16                   // chains per scan block
#define CSTR 545                // u32 stride per chain in LDS (32*17+1; ==1 mod 32)

typedef unsigned short u16;
typedef unsigned int   u32;
typedef _Float16 f16;
typedef f16   f16x8 __attribute__((ext_vector_type(8)));
typedef float f32x4 __attribute__((ext_vector_type(4)));

__device__ __forceinline__ float h2f(u16 u) { return __half2float(__ushort_as_half(u)); }
__device__ __forceinline__ u16   f2h(float f) { return __half_as_ushort(__float2half(f)); }
__device__ __forceinline__ u32   packh(float a, float b) {
    return (u32)f2h(a) | ((u32)f2h(b) << 16);
}

// ---------------- weight repack (all layers, one dispatch) + zero the bn counter
__global__ __launch_bounds__(256)
void wt_convert_all(const float* __restrict__ W0, const float* __restrict__ Wl,
                    u16* __restrict__ Wt0, u16* __restrict__ Wtl, u32* __restrict__ cnt) {
    if (blockIdx.x == 0 && threadIdx.x == 0) *cnt = 0;
    int id = blockIdx.x * 256 + threadIdx.x;
    const float* W; u16* outp; int NK, lg, chunk;
    if (id < 4096) { W = W0; outp = Wt0; NK = 4; lg = 2; chunk = id; }
    else {
        int r = id - 4096;
        int l = r >> 13;
        if (l >= 5) return;
        chunk = r & 8191;
        W = Wl + (size_t)l * H_DIM * H_DIM;
        outp = Wtl + (size_t)l * 65536;
        NK = 8; lg = 3;
    }
    int lane = chunk & 63;
    int rest = chunk >> 6;
    int n  = rest & 3; rest >>= 2;
    int kc = rest & (NK - 1);
    int w  = rest >> lg;
    int col = w * 64 + n + 4 * (lane & 15);
    int kb  = kc * 32 + (lane >> 4) * 8;
    u32 o[4];
    #pragma unroll
    for (int j = 0; j < 4; ++j)
        o[j] = packh(W[(size_t)(kb + 2 * j) * H_DIM + col],
                     W[(size_t)(kb + 2 * j + 1) * H_DIM + col]);
    *(uint4*)(outp + (size_t)chunk * 8) = uint4{o[0], o[1], o[2], o[3]};
}

// ---------------- MFMA GEMM, W-in-registers, fused bias + BN partial stats (f32).
template<int K, bool AF32>
__global__ __launch_bounds__(256, 2)
void gemm_mfma(const void* Asrc, const u16* __restrict__ Wtc,
               const float* __restrict__ bias, u16* Yout, float2* __restrict__ psum) {
    constexpr int NK = K / 32;
    constexpr int AROWB = AF32 ? 272 : 528;
    __shared__ char Alds[64 * AROWB];
    const int tid  = threadIdx.x;
    const int lane = tid & 63;
    const int wave = tid >> 6;
    const int c    = lane & 15;
    const int g    = lane >> 4;
    const size_t brow = (size_t)blockIdx.x * 64;

    f16x8 wreg[NK][4];
    {
        const u16* base = Wtc + ((size_t)wave * NK * 4 * 64 + lane) * 8;
        #pragma unroll
        for (int kc = 0; kc < NK; ++kc)
            #pragma unroll
            for (int n = 0; n < 4; ++n)
                wreg[kc][n] = *(const f16x8*)(base + (size_t)(kc * 4 + n) * 64 * 8);
    }
    {
        const char* A = (const char*)Asrc + brow * 512;
        #pragma unroll
        for (int i = 0; i < 8; ++i) {
            int off = i * 4096 + tid * 16;
            int row = off >> 9, inb = off & 511;
            if (AF32) {
                float4 v = *(const float4*)(A + off);
                uint2 o = { packh(v.x, v.y), packh(v.z, v.w) };
                *(uint2*)(Alds + row * AROWB + (inb >> 1)) = o;
            } else {
                *(uint4*)(Alds + row * AROWB + inb) = *(const uint4*)(A + off);
            }
        }
    }
    __syncthreads();

    f32x4 acc[4][4];
    #pragma unroll
    for (int m = 0; m < 4; ++m)
        #pragma unroll
        for (int n = 0; n < 4; ++n)
            acc[m][n] = f32x4{0.f, 0.f, 0.f, 0.f};

    #pragma unroll
    for (int kc = 0; kc < NK; ++kc) {
        f16x8 afr[4];
        #pragma unroll
        for (int m = 0; m < 4; ++m) {
            int row = m * 16 + c;
            afr[m] = *(const f16x8*)(Alds + row * AROWB + kc * 64 + (g << 4));
        }
        #pragma unroll
        for (int m = 0; m < 4; ++m)
            #pragma unroll
            for (int n = 0; n < 4; ++n)
                acc[m][n] = __builtin_amdgcn_mfma_f32_16x16x32_f16(afr[m], wreg[kc][n], acc[m][n], 0, 0, 0);
    }

    float4 bv = *(const float4*)(bias + wave * 64 + 4 * c);
    float bb[4] = {bv.x, bv.y, bv.z, bv.w};
    float s[4] = {}, q[4] = {};
    #pragma unroll
    for (int m = 0; m < 4; ++m) {
        #pragma unroll
        for (int r = 0; r < 4; ++r) {
            float y0 = acc[m][0][r] + bb[0];
            float y1 = acc[m][1][r] + bb[1];
            float y2 = acc[m][2][r] + bb[2];
            float y3 = acc[m][3][r] + bb[3];
            s[0] += y0; q[0] = fmaf(y0, y0, q[0]);
            s[1] += y1; q[1] = fmaf(y1, y1, q[1]);
            s[2] += y2; q[2] = fmaf(y2, y2, q[2]);
            s[3] += y3; q[3] = fmaf(y3, y3, q[3]);
            size_t grow = brow + m * 16 + g * 4 + r;
            ushort4 o = { f2h(y0), f2h(y1), f2h(y2), f2h(y3) };
            *(ushort4*)(Yout + grow * H_DIM + wave * 64 + 4 * c) = o;
        }
    }
    #pragma unroll
    for (int n = 0; n < 4; ++n) {
        s[n] += __shfl_xor(s[n], 16, 64); s[n] += __shfl_xor(s[n], 32, 64);
        q[n] += __shfl_xor(q[n], 16, 64); q[n] += __shfl_xor(q[n], 32, 64);
    }
    if (g == 0) {
        float2* dst = psum + (size_t)blockIdx.x * 256 + wave * 64 + 4 * c;
        #pragma unroll
        for (int n = 0; n < 4; ++n) dst[n] = float2{s[n], q[n]};
    }
}

// ---------------- BN reduce + finalize (last-block pattern, deterministic)
__global__ __launch_bounds__(256)
void bn_reduce_fin(const float2* __restrict__ psum, float2* __restrict__ p2,
                   const float* __restrict__ gamma, const float* __restrict__ beta,
                   float* __restrict__ af, float* __restrict__ shf, u32* cnt) {
    const int cch = threadIdx.x, blk = blockIdx.x;
    float s = 0.f, q = 0.f;
    for (int i = 0; i < 32; ++i) {
        float2 p = psum[(size_t)(blk * 32 + i) * 256 + cch];
        s += p.x; q += p.y;
    }
    p2[blk * 256 + cch] = float2{s, q};
    __threadfence();
    __shared__ u32 lastFlag;
    if (threadIdx.x == 0) lastFlag = (atomicAdd(cnt, 1) == 63) ? 1u : 0u;
    __syncthreads();
    if (lastFlag) {
        __threadfence();
        float ss = 0.f, qq = 0.f;
        for (int i = 0; i < 64; ++i) {
            float2 v = p2[i * 256 + cch];
            ss += v.x; qq += v.y;
        }
        const float inv = 1.0f / (float)M_DIM;
        float m = ss * inv;
        float v = qq * inv - m * m;
        float a = gamma[cch] * rsqrtf(v + 1e-5f);
        af[cch] = a;
        shf[cch] = fmaf(-m, a, beta[cch]);
        if (threadIdx.x == 0) atomicExch(cnt, 0);
    }
}

// ---------------- fused scan: r12 access pattern, T split in 2 sequential tiles
// with exact carry. LDS 34.9 KB -> 4 blocks/CU (32 waves/CU) for phase overlap.
// Thread (c,j): chain c 0..15, chunk j 0..31 of 32 timesteps (16 u32) per tile.
__global__ __launch_bounds__(512, 8)
void scan_fused(u16* act, const float* __restrict__ af, const float* __restrict__ shf,
                const float* __restrict__ uw) {
    __shared__ u32 Y32[CB * CSTR];                            // 34880 B
    const int tid = threadIdx.x;
    const int nwg = gridDim.x;                                // 1024
    const int cb  = (blockIdx.x & 7) * (nwg >> 3) + (blockIdx.x >> 3);  // XCD swizzle
    u32* actG = (u32*)act;
    const int gcb = cb * 8;                                   // 8 u32 cols (16 chains)
    const int hf = tid & 1;                                   // 16B half of the 32B row slice
    const int qb = tid >> 1;                                  // 0..255
    const int c = tid >> 5;                                   // chain 0..15
    const int j = tid & 31;                                   // chunk 0..31
    const int cch = (cb * CB + c) & (H_DIM - 1);
    const float A = af[cch], SH = shf[cch], U = uw[cch];
    const int ybase = c * CSTR + j * 17;

    float carry = 0.f;
    for (int tt = 0; tt < 2; ++tt) {
        const size_t tbase = (size_t)tt * 1024;               // global t offset

        // ---- stage: rows (2q,2q+1) x 16B half -> 8 packed chain u32s
        #pragma unroll
        for (int it = 0; it < 2; ++it) {
            int q = qb + it * 256;                            // local t-pair 0..511
            size_t rg = tbase + 2 * q;
            uint4 ve = *(const uint4*)(actG + rg * 8192 + gcb + hf * 4);
            uint4 vo = *(const uint4*)(actG + (rg + 1) * 8192 + gcb + hf * 4);
            int ofs = (q >> 4) * 17 + (q & 15);
            u32 e[4] = {ve.x, ve.y, ve.z, ve.w};
            u32 o[4] = {vo.x, vo.y, vo.z, vo.w};
            #pragma unroll
            for (int m = 0; m < 4; ++m) {
                int ch = hf * 8 + 2 * m;
                Y32[ch * CSTR + ofs]       = (e[m] & 0xFFFFu) | (o[m] << 16);
                Y32[(ch + 1) * CSTR + ofs] = (e[m] >> 16)     | (o[m] & 0xFFFF0000u);
            }
        }
        __syncthreads();

        // ---- compose my 16-u32 chunk (32 steps) in registers
        u32 yw[16];
        #pragma unroll
        for (int k = 0; k < 16; ++k) yw[k] = Y32[ybase + k];
        float a = 1.f, b = 0.f, cm = -1e30f;                  // identity; -1e30 avoids 0*inf
        #pragma unroll
        for (int k = 0; k < 16; ++k) {
            u32 w = yw[k];
            float yn0 = fmaf(A, h2f((u16)(w & 0xFFFF)), SH);
            a *= U; b = fmaf(U, b, yn0); cm = fmaxf(fmaf(U, cm, yn0), 0.f);
            float yn1 = fmaf(A, h2f((u16)(w >> 16)), SH);
            a *= U; b = fmaf(U, b, yn1); cm = fmaxf(fmaf(U, cm, yn1), 0.f);
        }

        // ---- Kogge-Stone inclusive compose-scan over 32 chunks of the chain
        #pragma unroll
        for (int d = 1; d < 32; d <<= 1) {
            float ai = __shfl_up(a, d, 32);
            float bi = __shfl_up(b, d, 32);
            float ci = __shfl_up(cm, d, 32);
            if (j >= d) {                     // outer=(a,b,cm) ∘ inner=(ai,bi,ci)
                float nb = fmaf(a, bi, b);
                float nc = fmaxf(fmaf(a, ci, b), cm);
                a *= ai; b = nb; cm = nc;
            }
        }
        // exclusive composite -> h_in for my chunk (applied to the carry)
        float ae = __shfl_up(a, 1, 32);
        float be = __shfl_up(b, 1, 32);
        float ce = __shfl_up(cm, 1, 32);
        float hin = (j == 0) ? carry : fmaxf(fmaf(ae, carry, be), ce);
        // update carry with the full-tile (lane 31) inclusive composite
        float a31 = __shfl(a, 31, 32);
        float b31 = __shfl(b, 31, 32);
        float c31 = __shfl(cm, 31, 32);
        carry = fmaxf(fmaf(a31, carry, b31), c31);

        // ---- apply from registers, pack h back into my Y32 slice
        {
            float h = hin;
            #pragma unroll
            for (int k = 0; k < 16; ++k) {
                u32 w = yw[k];
                h = fmaxf(fmaf(U, h, fmaf(A, h2f((u16)(w & 0xFFFF)), SH)), 0.f);
                float hl = h;
                h = fmaxf(fmaf(U, h, fmaf(A, h2f((u16)(w >> 16)), SH)), 0.f);
                Y32[ybase + k] = packh(hl, h);
            }
        }
        __syncthreads();

        // ---- writeback: inverse of stage (32B/row per block, no partial sectors)
        #pragma unroll
        for (int it = 0; it < 2; ++it) {
            int q = qb + it * 256;
            size_t rg = tbase + 2 * q;
            int ofs = (q >> 4) * 17 + (q & 15);
            u32 e[4], o[4];
            #pragma unroll
            for (int m = 0; m < 4; ++m) {
                int ch = hf * 8 + 2 * m;
                u32 p0 = Y32[ch * CSTR + ofs];
                u32 p1 = Y32[(ch + 1) * CSTR + ofs];
                e[m] = (p0 & 0xFFFFu) | ((p1 & 0xFFFFu) << 16);
                o[m] = (p0 >> 16)     | (p1 & 0xFFFF0000u);
            }
            *(uint4*)(actG + rg * 8192 + gcb + hf * 4)       = uint4{e[0], e[1], e[2], e[3]};
            *(uint4*)(actG + (rg + 1) * 8192 + gcb + hf * 4) = uint4{o[0], o[1], o[2], o[3]};
        }
        __syncthreads();
    }
}

// ---------------- classifier: out[B,C] = h_last[B,H] @ Wc[H,C] + bc (f32 out)
__global__ __launch_bounds__(128)
void classifier(const u16* __restrict__ Hlast, const float* __restrict__ Wc,
                const float* __restrict__ bc, float* __restrict__ out) {
    __shared__ float hrow[H_DIM];
    const int b = blockIdx.x, tid = threadIdx.x;
    hrow[tid]       = h2f(Hlast[(size_t)b * H_DIM + tid]);
    hrow[tid + 128] = h2f(Hlast[(size_t)b * H_DIM + tid + 128]);
    __syncthreads();
    if (tid < C_DIM) {
        float s = bc[tid];
        #pragma unroll 8
        for (int hh = 0; hh < H_DIM; ++hh)
            s = fmaf(hrow[hh], Wc[(size_t)hh * C_DIM + tid], s);
        out[(size_t)b * C_DIM + tid] = s;
    }
}

extern "C" void kernel_launch(void* const* d_in, const int* in_sizes, int n_in,
                              void* d_out, int out_size, void* d_ws, size_t ws_size,
                              hipStream_t stream) {
    const float* x     = (const float*)d_in[0];
    const float* W0    = (const float*)d_in[1];
    const float* b0    = (const float*)d_in[2];
    const float* Wl    = (const float*)d_in[3];
    const float* bl    = (const float*)d_in[4];
    const float* u     = (const float*)d_in[5];
    const float* gamma = (const float*)d_in[6];
    const float* beta  = (const float*)d_in[7];
    const float* Wc    = (const float*)d_in[8];
    const float* bc    = (const float*)d_in[9];
    float* out = (float*)d_out;

    // workspace (~72 MB)
    char* ws = (char*)d_ws;
    u16* act = (u16*)ws;                 ws += (size_t)M_DIM * H_DIM * 2;   // 67.1 MB
    u16* Wt0 = (u16*)ws;                 ws += (size_t)32768 * 2;           // 64 KB
    u16* Wtl = (u16*)ws;                 ws += (size_t)5 * 65536 * 2;       // 640 KB
    float2* psum = (float2*)ws;          ws += (size_t)2048 * 256 * 8;      // 4 MB
    float2* p2 = (float2*)ws;            ws += (size_t)64 * 256 * 8;        // 128 KB
    float* af  = (float*)ws;             ws += H_DIM * 4;
    float* shf = (float*)ws;             ws += H_DIM * 4;
    u32* cnt   = (u32*)ws;               ws += 256;

    wt_convert_all<<<176, 256, 0, stream>>>(W0, Wl, Wt0, Wtl, cnt);

    for (int l = 0; l < L_DIM; ++l) {
        if (l == 0) {
            gemm_mfma<I_DIM, true><<<M_DIM / 64, 256, 0, stream>>>(x, Wt0, b0, act, psum);
        } else {
            gemm_mfma<H_DIM, false><<<M_DIM / 64, 256, 0, stream>>>(
                act, Wtl + (size_t)(l - 1) * 65536, bl + (size_t)(l - 1) * H_DIM, act, psum);
        }
        bn_reduce_fin<<<64, 256, 0, stream>>>(psum, p2, gamma + l * H_DIM,
                                              beta + l * H_DIM, af, shf, cnt);
        scan_fused<<<S_DIM / CB, 512, 0, stream>>>(act, af, shf, u + l * H_DIM);
    }
    classifier<<<B_DIM, 128, 0, stream>>>(act + (size_t)(T_DIM - 1) * S_DIM, Wc, bc, out);
}